// Round 7
// baseline (757.009 us; speedup 1.0000x reference)
//
#include <hip/hip_runtime.h>
#include <hip/hip_bf16.h>

using bf16 = __hip_bfloat16;

#define NEG_SLOPE 0.01f

// ---------------------------------------------------------------------------
// k_zero
// ---------------------------------------------------------------------------
__global__ void k_zero(unsigned int* __restrict__ p, int n) {
  int i = blockIdx.x * 256 + threadIdx.x;
  if (i < n) p[i] = 0u;
}

// ---------------------------------------------------------------------------
// k_prep: fold e = r@rel_w.T + rel_b through the attention vectors + all
// scalar biases into per-layer constants.
//   consts[0..31]=v1, consts[32..63]=v2, consts[64]=c1, consts[65]=c2
// ---------------------------------------------------------------------------
__global__ void k_prep(const float* __restrict__ rel_w, const float* __restrict__ rel_b,
                       const float* __restrict__ ew1_w, const float* __restrict__ ew1_b,
                       const float* __restrict__ ew2_w, const float* __restrict__ ew2_b,
                       const float* __restrict__ ai1_b, const float* __restrict__ aj1_b,
                       const float* __restrict__ ai2_b, const float* __restrict__ aj2_b,
                       float* __restrict__ consts) {
  int t = threadIdx.x;
  if (t < 32) {
    float a1 = 0.f, a2 = 0.f;
    for (int o = 0; o < 64; ++o) {
      float w = rel_w[o * 32 + t];
      a1 += w * ew1_w[o];
      a2 += w * ew2_w[o];
    }
    consts[t] = a1;
    consts[32 + t] = a2;
  } else if (t == 32) {
    float c = 0.f;
    for (int o = 0; o < 64; ++o) c += rel_b[o] * ew1_w[o];
    consts[64] = c + ew1_b[0] + ai1_b[0] + aj1_b[0];
  } else if (t == 33) {
    float c = 0.f;
    for (int o = 0; o < 64; ++o) c += rel_b[o] * ew2_w[o];
    consts[65] = c + ew2_b[0] + ai2_b[0] + aj2_b[0];
  }
}

// ---------------------------------------------------------------------------
// CSR degree + 3-phase parallel scan
// ---------------------------------------------------------------------------
__global__ void k_deg(const int* __restrict__ dst, int* __restrict__ deg, int E) {
  int e = blockIdx.x * 256 + threadIdx.x;
  if (e < E) atomicAdd(&deg[dst[e]], 1);
}

__global__ __launch_bounds__(256) void k_scan_sum(const int* __restrict__ deg,
                                                  int* __restrict__ bsum, int N) {
  __shared__ int ws_[4];
  int t = threadIdx.x;
  int i = blockIdx.x * 256 + t;
  int v = (i < N) ? deg[i] : 0;
  #pragma unroll
  for (int m = 32; m >= 1; m >>= 1) v += __shfl_xor(v, m, 64);
  if ((t & 63) == 0) ws_[t >> 6] = v;
  __syncthreads();
  if (t == 0) bsum[blockIdx.x] = ws_[0] + ws_[1] + ws_[2] + ws_[3];
}

__global__ __launch_bounds__(256) void k_scan_bsum(const int* __restrict__ bsum,
                                                   int* __restrict__ bsumx,
                                                   int* __restrict__ off,
                                                   int NB, int N, int E) {
  __shared__ int part[256];
  int t = threadIdx.x;
  part[t] = (t < NB) ? bsum[t] : 0;
  __syncthreads();
  for (int d = 1; d < 256; d <<= 1) {
    int v = (t >= d) ? part[t - d] : 0;
    __syncthreads();
    part[t] += v;
    __syncthreads();
  }
  if (t < NB) bsumx[t] = (t == 0) ? 0 : part[t - 1];
  if (t == 0) off[N] = E;
}

__global__ __launch_bounds__(256) void k_scan_out(const int* __restrict__ deg,
                                                  const int* __restrict__ bsumx,
                                                  int* __restrict__ off,
                                                  int* __restrict__ pos, int N) {
  __shared__ int wsum[4];
  int t = threadIdx.x;
  int lane = t & 63;
  int wave = t >> 6;
  int i = blockIdx.x * 256 + t;
  int v = (i < N) ? deg[i] : 0;
  int incl = v;
  #pragma unroll
  for (int d = 1; d < 64; d <<= 1) {
    int u = __shfl_up(incl, d, 64);
    if (lane >= d) incl += u;
  }
  int wtot = __shfl(incl, 63, 64);
  if (lane == 0) wsum[wave] = wtot;
  __syncthreads();
  int woff = 0;
  for (int w = 0; w < 4; ++w) woff += (w < wave) ? wsum[w] : 0;
  if (i < N) {
    int o = bsumx[blockIdx.x] + woff + (incl - v);
    off[i] = o;
    pos[i] = o;
  }
}

// ---------------------------------------------------------------------------
// k_build: fused CSR fill + edge preprocessing. One 32-lane group per edge,
// e-order (all global READS sequential; only writes are scattered, which
// don't stall the wave). Per edge:
//   p = atomicAdd(pos[dst])                  (CSR slot)
//   r_s[p]   = bf16(r[e])                    (64B scatter)
//   ewd1_s[p], ewd2_s[p] = r[e].v? + c?      (both layers' attention dots,
//                                             computed from f32 r)
//   src_s[p], dst_s[p]   = u16 endpoints
// ---------------------------------------------------------------------------
__global__ void k_build(const int* __restrict__ src, const int* __restrict__ dst,
                        const float* __restrict__ r, const float* __restrict__ consts,
                        int* __restrict__ pos,
                        float* __restrict__ ewd1_s, float* __restrict__ ewd2_s,
                        unsigned short* __restrict__ src_s,
                        unsigned short* __restrict__ dst_s,
                        bf16* __restrict__ r_s, int E) {
  int t = threadIdx.x;
  int k = t & 31;
  int e = blockIdx.x * 8 + (t >> 5);
  if (e >= E) return;
  int d = dst[e];  // same address across the 32-lane group -> broadcast
  int p = 0;
  if (k == 0) p = atomicAdd(&pos[d], 1);
  p = __shfl(p, 0, 32);  // broadcast CSR slot within the group
  float rv = r[(size_t)e * 32 + k];
  r_s[(size_t)p * 32 + k] = __float2bfloat16(rv);
  float p1 = rv * consts[k];
  float p2 = rv * consts[32 + k];
  #pragma unroll
  for (int m = 16; m >= 1; m >>= 1) {  // stays within the 32-lane group
    p1 += __shfl_xor(p1, m, 64);
    p2 += __shfl_xor(p2, m, 64);
  }
  if (k == 0) {
    ewd1_s[p] = p1 + consts[64];
    ewd2_s[p] = p2 + consts[65];
    src_s[p] = (unsigned short)src[e];
    dst_s[p] = (unsigned short)d;
  }
}

// ---------------------------------------------------------------------------
// k_x: x[n] = in[n] @ W.T + b (bf16 out), plus aid/ajd per-node scalars (f32).
// ---------------------------------------------------------------------------
__global__ __launch_bounds__(256) void k_x(const float* __restrict__ in,
                                           const float* __restrict__ W,
                                           const float* __restrict__ b,
                                           const float* __restrict__ ai_w,
                                           const float* __restrict__ aj_w,
                                           bf16* __restrict__ x,
                                           float* __restrict__ aid,
                                           float* __restrict__ ajd, int N) {
  __shared__ float WT[64 * 64];
  int t = threadIdx.x;
  for (int idx = t; idx < 4096; idx += 256) {
    int o = idx >> 6, c = idx & 63;
    WT[c * 64 + o] = W[idx];
  }
  __syncthreads();
  int l = t & 63;
  int wave = t >> 6;
  int nwaves = gridDim.x * 4;
  float aw = ai_w[l], jw = aj_w[l], bl = b[l];
  for (int n = blockIdx.x * 4 + wave; n < N; n += nwaves) {
    float xin = in[(size_t)n * 64 + l];
    float acc = bl;
    #pragma unroll
    for (int c = 0; c < 64; ++c) {
      float bc = __shfl(xin, c, 64);
      acc += bc * WT[c * 64 + l];
    }
    x[(size_t)n * 64 + l] = __float2bfloat16(acc);
    float pa = acc * aw, pj = acc * jw;
    #pragma unroll
    for (int m = 32; m >= 1; m >>= 1) {
      pa += __shfl_xor(pa, m, 64);
      pj += __shfl_xor(pj, m, 64);
    }
    if (l == 0) { aid[n] = pa; ajd[n] = pj; }
  }
}

// ---------------------------------------------------------------------------
// k_alpha: all-sequential except small L2-resident gathers (aid near-seq since
// consecutive p share dst; ajd/s random into 200KB tables).
// ---------------------------------------------------------------------------
__global__ void k_alpha(const unsigned short* __restrict__ src_s,
                        const unsigned short* __restrict__ dst_s,
                        const float* __restrict__ aid, const float* __restrict__ ajd,
                        const float* __restrict__ ewd,
                        float* __restrict__ ex, float* __restrict__ s, int E) {
  int p = blockIdx.x * 256 + threadIdx.x;
  if (p >= E) return;
  int sn = src_s[p];
  int dn = dst_s[p];
  float a = aid[dn] + ajd[sn] + ewd[p];
  a = (a > 0.f) ? a : a * NEG_SLOPE;
  float ev = __expf(a);
  ex[p] = ev;
  atomicAdd(&s[sn], ev);
}

// ---------------------------------------------------------------------------
// k_norm: ex[p] /= (s[src_s[p]] + 1e-16)
// ---------------------------------------------------------------------------
__global__ void k_norm(const unsigned short* __restrict__ src_s,
                       float* __restrict__ ex,
                       const float* __restrict__ s, int E) {
  int p = blockIdx.x * 256 + threadIdx.x;
  if (p >= E) return;
  ex[p] = ex[p] / (s[src_s[p]] + 1e-16f);
}

// ---------------------------------------------------------------------------
// k_agg: atomic-free aggregation over CSR-by-dst, one wave per node.
// x gathered as bf16 (one 128B line per row); r_s read as sequential bf16
// stream (wave covers 2 edges = 128B per load).
// ---------------------------------------------------------------------------
__global__ __launch_bounds__(256) void k_agg(const int* __restrict__ off,
                                             const unsigned short* __restrict__ src_s,
                                             const float* __restrict__ ex,
                                             const bf16* __restrict__ x,
                                             const bf16* __restrict__ r_s,
                                             const float* __restrict__ rel_w,
                                             const float* __restrict__ rel_b,
                                             float* __restrict__ out, int N) {
  __shared__ float RT[32 * 64];  // RT[k][o] = rel_w[o][k]
  int t = threadIdx.x;
  for (int idx = t; idx < 2048; idx += 256) {
    int o = idx >> 5, k = idx & 31;
    RT[k * 64 + o] = rel_w[idx];
  }
  __syncthreads();
  int l = t & 63;
  int k31 = l & 31;
  bool lohalf = (l < 32);
  int hsel = lohalf ? 0 : 1;
  int wave = t >> 6;
  int nwaves = gridDim.x * 4;
  float rbl = rel_b[l];
  for (int n = blockIdx.x * 4 + wave; n < N; n += nwaves) {
    int p0 = off[n], p1 = off[n + 1];
    float accx = 0.f, accq = 0.f, wsum = 0.f;
    int p = p0;
    for (; p + 4 <= p1; p += 4) {
      int s0 = src_s[p], s1 = src_s[p + 1], s2 = src_s[p + 2], s3 = src_s[p + 3];
      float w0 = ex[p], w1 = ex[p + 1], w2 = ex[p + 2], w3 = ex[p + 3];
      // 4 independent 128B row gathers in flight (bf16 row = 1 cacheline)
      float x0 = __bfloat162float(x[(size_t)s0 * 64 + l]);
      float x1 = __bfloat162float(x[(size_t)s1 * 64 + l]);
      float x2 = __bfloat162float(x[(size_t)s2 * 64 + l]);
      float x3 = __bfloat162float(x[(size_t)s3 * 64 + l]);
      float wa = lohalf ? w0 : w1;
      float wb = lohalf ? w2 : w3;
      // sequential bf16 stream: each load covers 2 edges = 128B/wave
      float ra = __bfloat162float(r_s[(size_t)(p + hsel) * 32 + k31]);
      float rb = __bfloat162float(r_s[(size_t)(p + 2 + hsel) * 32 + k31]);
      accx += w0 * x0 + w1 * x1 + w2 * x2 + w3 * x3;
      accq += wa * ra + wb * rb;
      wsum += w0 + w1 + w2 + w3;
    }
    for (; p < p1; ++p) {
      int sn = src_s[p];
      float w = ex[p];
      accx += w * __bfloat162float(x[(size_t)sn * 64 + l]);
      if (lohalf) accq += w * __bfloat162float(r_s[(size_t)p * 32 + k31]);
      wsum += w;
    }
    accq += __shfl_xor(accq, 32, 64);  // fold half-wave partials
    float acc = accx + wsum * rbl;
    #pragma unroll
    for (int k = 0; k < 32; ++k) {
      float qk = __shfl(accq, k, 64);
      acc += qk * RT[k * 64 + l];
    }
    out[(size_t)n * 64 + l] = fmaxf(acc, 0.f);
  }
}

// ---------------------------------------------------------------------------
extern "C" void kernel_launch(void* const* d_in, const int* in_sizes, int n_in,
                              void* d_out, int out_size, void* d_ws, size_t ws_size,
                              hipStream_t stream) {
  const float* feat   = (const float*)d_in[0];
  const int*   eidx   = (const int*)d_in[1];
  const float* r      = (const float*)d_in[2];
  const float* rel_w  = (const float*)d_in[3];
  const float* rel_b  = (const float*)d_in[4];
  const float* c1_lw  = (const float*)d_in[5];
  const float* c1_lb  = (const float*)d_in[6];
  const float* c1_aiw = (const float*)d_in[7];
  const float* c1_aib = (const float*)d_in[8];
  const float* c1_ajw = (const float*)d_in[9];
  const float* c1_ajb = (const float*)d_in[10];
  const float* c1_eww = (const float*)d_in[11];
  const float* c1_ewb = (const float*)d_in[12];
  const float* c2_lw  = (const float*)d_in[13];
  const float* c2_lb  = (const float*)d_in[14];
  const float* c2_aiw = (const float*)d_in[15];
  const float* c2_aib = (const float*)d_in[16];
  const float* c2_ajw = (const float*)d_in[17];
  const float* c2_ajb = (const float*)d_in[18];
  const float* c2_eww = (const float*)d_in[19];
  const float* c2_ewb = (const float*)d_in[20];
  float* out = (float*)d_out;

  const int N = in_sizes[0] / 64;
  const int E = in_sizes[1] / 2;
  const int* src = eidx;
  const int* dst = eidx + E;

  // ---- workspace carve (~85 MB; R6 proved ws_size >= 94 MB) ----
  float* wsf    = (float*)d_ws;
  float* consts = wsf;                          // 128
  float* ewd1_s = wsf + 128;                    // E (p-order)
  float* ewd2_s = ewd1_s + E;                   // E
  float* ex     = ewd2_s + E;                   // E
  float* s      = ex + E;                       // N
  float* aid    = s + N;                        // N
  float* ajd    = aid + N;                      // N
  float* h1     = ajd + N;                      // N*64 f32 (inter-layer, seq)
  bf16*  x      = (bf16*)(h1 + (size_t)N * 64); // N*64 bf16 (gathered table)
  int*   deg    = (int*)(x + (size_t)N * 64);   // N
  int*   off    = deg + N;                      // N+1
  int*   pos    = off + N + 1;                  // N
  int*   bsum   = pos + N;                      // 256
  int*   bsumx  = bsum + 256;                   // 256
  unsigned short* src_s = (unsigned short*)(bsumx + 256);  // E u16
  unsigned short* dst_s = src_s + E;                       // E u16
  bf16* r_s = (bf16*)(dst_s + E);                          // E*32 bf16

  const int blocksE  = (E + 255) / 256;
  const int blocksE8 = (E + 7) / 8;
  const int blocksN  = (N + 255) / 256;
  const int gridP    = 2048;

  // ---- shared prep (both layers) ----
  k_zero<<<blocksN, 256, 0, stream>>>((unsigned int*)deg, N);
  k_prep<<<1, 64, 0, stream>>>(rel_w, rel_b, c1_eww, c1_ewb, c2_eww, c2_ewb,
                               c1_aib, c1_ajb, c2_aib, c2_ajb, consts);
  k_deg<<<blocksE, 256, 0, stream>>>(dst, deg, E);
  k_scan_sum<<<blocksN, 256, 0, stream>>>(deg, bsum, N);
  k_scan_bsum<<<1, 256, 0, stream>>>(bsum, bsumx, off, blocksN, N, E);
  k_scan_out<<<blocksN, 256, 0, stream>>>(deg, bsumx, off, pos, N);
  k_build<<<blocksE8, 256, 0, stream>>>(src, dst, r, consts, pos,
                                        ewd1_s, ewd2_s, src_s, dst_s, r_s, E);

  // ---- layer 1 ----
  k_zero<<<blocksN, 256, 0, stream>>>((unsigned int*)s, N);
  k_x<<<gridP, 256, 0, stream>>>(feat, c1_lw, c1_lb, c1_aiw, c1_ajw, x, aid, ajd, N);
  k_alpha<<<blocksE, 256, 0, stream>>>(src_s, dst_s, aid, ajd, ewd1_s, ex, s, E);
  k_norm<<<blocksE, 256, 0, stream>>>(src_s, ex, s, E);
  k_agg<<<gridP, 256, 0, stream>>>(off, src_s, ex, x, r_s, rel_w, rel_b, h1, N);

  // ---- layer 2 ----
  k_zero<<<blocksN, 256, 0, stream>>>((unsigned int*)s, N);
  k_x<<<gridP, 256, 0, stream>>>(h1, c2_lw, c2_lb, c2_aiw, c2_ajw, x, aid, ajd, N);
  k_alpha<<<blocksE, 256, 0, stream>>>(src_s, dst_s, aid, ajd, ewd2_s, ex, s, E);
  k_norm<<<blocksE, 256, 0, stream>>>(src_s, ex, s, E);
  k_agg<<<gridP, 256, 0, stream>>>(off, src_s, ex, x, r_s, rel_w, rel_b, out, N);
}

// Round 9
// 694.549 us; speedup vs baseline: 1.0899x; 1.0899x over previous
//
#include <hip/hip_runtime.h>
#include <hip/hip_bf16.h>

using bf16 = __hip_bfloat16;

#define NEG_SLOPE 0.01f

// ---------------------------------------------------------------------------
// k_zero: one dispatch zeroing the contiguous {s1, s2, deg} region (3N words)
// ---------------------------------------------------------------------------
__global__ void k_zero(unsigned int* __restrict__ p, int n) {
  int i = blockIdx.x * 256 + threadIdx.x;
  if (i < n) p[i] = 0u;
}

// ---------------------------------------------------------------------------
// k_prep: fold e = r@rel_w.T + rel_b through the attention vectors + all
// scalar biases into per-layer constants.
//   consts[0..31]=v1, consts[32..63]=v2, consts[64]=c1, consts[65]=c2
// ---------------------------------------------------------------------------
__global__ void k_prep(const float* __restrict__ rel_w, const float* __restrict__ rel_b,
                       const float* __restrict__ ew1_w, const float* __restrict__ ew1_b,
                       const float* __restrict__ ew2_w, const float* __restrict__ ew2_b,
                       const float* __restrict__ ai1_b, const float* __restrict__ aj1_b,
                       const float* __restrict__ ai2_b, const float* __restrict__ aj2_b,
                       float* __restrict__ consts) {
  int t = threadIdx.x;
  if (t < 32) {
    float a1 = 0.f, a2 = 0.f;
    for (int o = 0; o < 64; ++o) {
      float w = rel_w[o * 32 + t];
      a1 += w * ew1_w[o];
      a2 += w * ew2_w[o];
    }
    consts[t] = a1;
    consts[32 + t] = a2;
  } else if (t == 32) {
    float c = 0.f;
    for (int o = 0; o < 64; ++o) c += rel_b[o] * ew1_w[o];
    consts[64] = c + ew1_b[0] + ai1_b[0] + aj1_b[0];
  } else if (t == 33) {
    float c = 0.f;
    for (int o = 0; o < 64; ++o) c += rel_b[o] * ew2_w[o];
    consts[65] = c + ew2_b[0] + ai2_b[0] + aj2_b[0];
  }
}

// ---------------------------------------------------------------------------
// k_deg: 4 edges per thread (vectorized read), atomic degree count.
// ---------------------------------------------------------------------------
__global__ void k_deg(const int* __restrict__ dst, int* __restrict__ deg, int E) {
  int e4 = (blockIdx.x * 256 + threadIdx.x) * 4;
  if (e4 + 3 < E) {
    int4 d = *(const int4*)(dst + e4);
    atomicAdd(&deg[d.x], 1);
    atomicAdd(&deg[d.y], 1);
    atomicAdd(&deg[d.z], 1);
    atomicAdd(&deg[d.w], 1);
  } else {
    for (int e = e4; e < E; ++e) atomicAdd(&deg[dst[e]], 1);
  }
}

// ---------------------------------------------------------------------------
// 3-phase parallel exclusive scan (N ~ 50k, NB <= 256)
// ---------------------------------------------------------------------------
__global__ __launch_bounds__(256) void k_scan_sum(const int* __restrict__ deg,
                                                  int* __restrict__ bsum, int N) {
  __shared__ int ws_[4];
  int t = threadIdx.x;
  int i = blockIdx.x * 256 + t;
  int v = (i < N) ? deg[i] : 0;
  #pragma unroll
  for (int m = 32; m >= 1; m >>= 1) v += __shfl_xor(v, m, 64);
  if ((t & 63) == 0) ws_[t >> 6] = v;
  __syncthreads();
  if (t == 0) bsum[blockIdx.x] = ws_[0] + ws_[1] + ws_[2] + ws_[3];
}

__global__ __launch_bounds__(256) void k_scan_bsum(const int* __restrict__ bsum,
                                                   int* __restrict__ bsumx,
                                                   int* __restrict__ off,
                                                   int NB, int N, int E) {
  __shared__ int part[256];
  int t = threadIdx.x;
  part[t] = (t < NB) ? bsum[t] : 0;
  __syncthreads();
  for (int d = 1; d < 256; d <<= 1) {
    int v = (t >= d) ? part[t - d] : 0;
    __syncthreads();
    part[t] += v;
    __syncthreads();
  }
  if (t < NB) bsumx[t] = (t == 0) ? 0 : part[t - 1];
  if (t == 0) off[N] = E;
}

__global__ __launch_bounds__(256) void k_scan_out(const int* __restrict__ deg,
                                                  const int* __restrict__ bsumx,
                                                  int* __restrict__ off,
                                                  int* __restrict__ pos, int N) {
  __shared__ int wsum[4];
  int t = threadIdx.x;
  int lane = t & 63;
  int wave = t >> 6;
  int i = blockIdx.x * 256 + t;
  int v = (i < N) ? deg[i] : 0;
  int incl = v;
  #pragma unroll
  for (int d = 1; d < 64; d <<= 1) {
    int u = __shfl_up(incl, d, 64);
    if (lane >= d) incl += u;
  }
  int wtot = __shfl(incl, 63, 64);
  if (lane == 0) wsum[wave] = wtot;
  __syncthreads();
  int woff = 0;
  for (int w = 0; w < 4; ++w) woff += (w < wave) ? wsum[w] : 0;
  if (i < N) {
    int o = bsumx[blockIdx.x] + woff + (incl - v);
    off[i] = o;
    pos[i] = o;
  }
}

// ---------------------------------------------------------------------------
// k_fill: e-order; scatters only the SMALL payload (8B/edge) into CSR slots.
// ---------------------------------------------------------------------------
__global__ void k_fill(const int* __restrict__ src, const int* __restrict__ dst,
                       int* __restrict__ pos, int* __restrict__ eid_s,
                       unsigned short* __restrict__ src_s,
                       unsigned short* __restrict__ dst_s, int E) {
  int e = blockIdx.x * 256 + threadIdx.x;
  if (e >= E) return;
  int d = dst[e];
  int p = atomicAdd(&pos[d], 1);
  eid_s[p] = e;
  src_s[p] = (unsigned short)src[e];
  dst_s[p] = (unsigned short)d;
}

// ---------------------------------------------------------------------------
// k_perm: p-order; gathers the BIG payload (r rows, 128B lines) with 4
// independent loads in flight per 32-lane group, writes r_s (bf16) + both
// layers' attention dots sequentially. Writes are clean (no amplification).
// ---------------------------------------------------------------------------
__global__ __launch_bounds__(256) void k_perm(const int* __restrict__ eid_s,
                                              const float* __restrict__ r,
                                              const float* __restrict__ consts,
                                              float* __restrict__ ewd1_s,
                                              float* __restrict__ ewd2_s,
                                              bf16* __restrict__ r_s, int E) {
  int t = threadIdx.x;
  int k = t & 31;
  int g = blockIdx.x * 8 + (t >> 5);
  int p0 = g * 4;
  if (p0 >= E) return;
  float v1k = consts[k], v2k = consts[32 + k];
  float c1 = consts[64], c2 = consts[65];
  if (p0 + 4 <= E) {
    int e0 = eid_s[p0], e1 = eid_s[p0 + 1], e2 = eid_s[p0 + 2], e3 = eid_s[p0 + 3];
    // 4 independent 128B random row reads in flight
    float r0 = r[(size_t)e0 * 32 + k];
    float r1 = r[(size_t)e1 * 32 + k];
    float r2 = r[(size_t)e2 * 32 + k];
    float r3 = r[(size_t)e3 * 32 + k];
    // sequential bf16 writes: 256B contiguous per group
    r_s[(size_t)p0 * 32 + k]      = __float2bfloat16(r0);
    r_s[(size_t)p0 * 32 + 32 + k] = __float2bfloat16(r1);
    r_s[(size_t)p0 * 32 + 64 + k] = __float2bfloat16(r2);
    r_s[(size_t)p0 * 32 + 96 + k] = __float2bfloat16(r3);
    float a0 = r0 * v1k, b0 = r0 * v2k;
    float a1 = r1 * v1k, b1 = r1 * v2k;
    float a2 = r2 * v1k, b2 = r2 * v2k;
    float a3 = r3 * v1k, b3 = r3 * v2k;
    #pragma unroll
    for (int m = 16; m >= 1; m >>= 1) {
      a0 += __shfl_xor(a0, m, 64);  b0 += __shfl_xor(b0, m, 64);
      a1 += __shfl_xor(a1, m, 64);  b1 += __shfl_xor(b1, m, 64);
      a2 += __shfl_xor(a2, m, 64);  b2 += __shfl_xor(b2, m, 64);
      a3 += __shfl_xor(a3, m, 64);  b3 += __shfl_xor(b3, m, 64);
    }
    if (k == 0) {
      ewd1_s[p0]     = a0 + c1;  ewd2_s[p0]     = b0 + c2;
      ewd1_s[p0 + 1] = a1 + c1;  ewd2_s[p0 + 1] = b1 + c2;
      ewd1_s[p0 + 2] = a2 + c1;  ewd2_s[p0 + 2] = b2 + c2;
      ewd1_s[p0 + 3] = a3 + c1;  ewd2_s[p0 + 3] = b3 + c2;
    }
  } else {
    for (int p = p0; p < E; ++p) {
      int e = eid_s[p];
      float rv = r[(size_t)e * 32 + k];
      r_s[(size_t)p * 32 + k] = __float2bfloat16(rv);
      float a = rv * v1k, b = rv * v2k;
      #pragma unroll
      for (int m = 16; m >= 1; m >>= 1) {
        a += __shfl_xor(a, m, 64);
        b += __shfl_xor(b, m, 64);
      }
      if (k == 0) { ewd1_s[p] = a + c1; ewd2_s[p] = b + c2; }
    }
  }
}

// ---------------------------------------------------------------------------
// k_x: x[n] = in[n] @ W.T + b (bf16 out), plus aid/ajd per-node scalars (f32).
// ---------------------------------------------------------------------------
__global__ __launch_bounds__(256) void k_x(const float* __restrict__ in,
                                           const float* __restrict__ W,
                                           const float* __restrict__ b,
                                           const float* __restrict__ ai_w,
                                           const float* __restrict__ aj_w,
                                           bf16* __restrict__ x,
                                           float* __restrict__ aid,
                                           float* __restrict__ ajd, int N) {
  __shared__ float WT[64 * 64];
  int t = threadIdx.x;
  for (int idx = t; idx < 4096; idx += 256) {
    int o = idx >> 6, c = idx & 63;
    WT[c * 64 + o] = W[idx];
  }
  __syncthreads();
  int l = t & 63;
  int wave = t >> 6;
  int nwaves = gridDim.x * 4;
  float aw = ai_w[l], jw = aj_w[l], bl = b[l];
  for (int n = blockIdx.x * 4 + wave; n < N; n += nwaves) {
    float xin = in[(size_t)n * 64 + l];
    float acc = bl;
    #pragma unroll
    for (int c = 0; c < 64; ++c) {
      float bc = __shfl(xin, c, 64);
      acc += bc * WT[c * 64 + l];
    }
    x[(size_t)n * 64 + l] = __float2bfloat16(acc);
    float pa = acc * aw, pj = acc * jw;
    #pragma unroll
    for (int m = 32; m >= 1; m >>= 1) {
      pa += __shfl_xor(pa, m, 64);
      pj += __shfl_xor(pj, m, 64);
    }
    if (l == 0) { aid[n] = pa; ajd[n] = pj; }
  }
}

// ---------------------------------------------------------------------------
// k_alpha: p-order, all loads sequential or small-L2-table gathers.
//   ex[p] = exp(leaky_relu(aid[dst]+ajd[src]+ewd[p]));  s[src] += ex
// ---------------------------------------------------------------------------
__global__ void k_alpha(const unsigned short* __restrict__ src_s,
                        const unsigned short* __restrict__ dst_s,
                        const float* __restrict__ aid, const float* __restrict__ ajd,
                        const float* __restrict__ ewd,
                        float* __restrict__ ex, float* __restrict__ s, int E) {
  int p = blockIdx.x * 256 + threadIdx.x;
  if (p >= E) return;
  int sn = src_s[p];
  int dn = dst_s[p];
  float a = aid[dn] + ajd[sn] + ewd[p];
  a = (a > 0.f) ? a : a * NEG_SLOPE;
  float ev = __expf(a);
  ex[p] = ev;
  atomicAdd(&s[sn], ev);
}

// ---------------------------------------------------------------------------
// k_agg: atomic-free aggregation over CSR-by-dst, one wave per node.
// Softmax normalization fused: w = ex[p] * rcp(s[src]+eps) (s is a 200KB
// L2-resident table; rcp approx validated in R5 at absmax 2e-3).
// ---------------------------------------------------------------------------
__global__ __launch_bounds__(256) void k_agg(const int* __restrict__ off,
                                             const unsigned short* __restrict__ src_s,
                                             const float* __restrict__ ex,
                                             const float* __restrict__ s,
                                             const bf16* __restrict__ x,
                                             const bf16* __restrict__ r_s,
                                             const float* __restrict__ rel_w,
                                             const float* __restrict__ rel_b,
                                             float* __restrict__ out, int N) {
  __shared__ float RT[32 * 64];  // RT[k][o] = rel_w[o][k]
  int t = threadIdx.x;
  for (int idx = t; idx < 2048; idx += 256) {
    int o = idx >> 5, k = idx & 31;
    RT[k * 64 + o] = rel_w[idx];
  }
  __syncthreads();
  int l = t & 63;
  int k31 = l & 31;
  bool lohalf = (l < 32);
  int hsel = lohalf ? 0 : 1;
  int wave = t >> 6;
  int nwaves = gridDim.x * 4;
  float rbl = rel_b[l];
  for (int n = blockIdx.x * 4 + wave; n < N; n += nwaves) {
    int p0 = off[n], p1 = off[n + 1];
    float accx = 0.f, accq = 0.f, wsum = 0.f;
    int p = p0;
    for (; p + 4 <= p1; p += 4) {
      int s0 = src_s[p], s1 = src_s[p + 1], s2 = src_s[p + 2], s3 = src_s[p + 3];
      float w0 = ex[p]     * __builtin_amdgcn_rcpf(s[s0] + 1e-16f);
      float w1 = ex[p + 1] * __builtin_amdgcn_rcpf(s[s1] + 1e-16f);
      float w2 = ex[p + 2] * __builtin_amdgcn_rcpf(s[s2] + 1e-16f);
      float w3 = ex[p + 3] * __builtin_amdgcn_rcpf(s[s3] + 1e-16f);
      // 4 independent 128B row gathers in flight (bf16 row = 1 cacheline)
      float x0 = __bfloat162float(x[(size_t)s0 * 64 + l]);
      float x1 = __bfloat162float(x[(size_t)s1 * 64 + l]);
      float x2 = __bfloat162float(x[(size_t)s2 * 64 + l]);
      float x3 = __bfloat162float(x[(size_t)s3 * 64 + l]);
      float wa = lohalf ? w0 : w1;
      float wb = lohalf ? w2 : w3;
      // sequential bf16 stream: each load covers 2 edges = 128B/wave
      float ra = __bfloat162float(r_s[(size_t)(p + hsel) * 32 + k31]);
      float rb = __bfloat162float(r_s[(size_t)(p + 2 + hsel) * 32 + k31]);
      accx += w0 * x0 + w1 * x1 + w2 * x2 + w3 * x3;
      accq += wa * ra + wb * rb;
      wsum += w0 + w1 + w2 + w3;
    }
    for (; p < p1; ++p) {
      int sn = src_s[p];
      float w = ex[p] * __builtin_amdgcn_rcpf(s[sn] + 1e-16f);
      accx += w * __bfloat162float(x[(size_t)sn * 64 + l]);
      if (lohalf) accq += w * __bfloat162float(r_s[(size_t)p * 32 + k31]);
      wsum += w;
    }
    accq += __shfl_xor(accq, 32, 64);  // fold half-wave partials
    float acc = accx + wsum * rbl;
    #pragma unroll
    for (int k = 0; k < 32; ++k) {
      float qk = __shfl(accq, k, 64);
      acc += qk * RT[k * 64 + l];
    }
    out[(size_t)n * 64 + l] = fmaxf(acc, 0.f);
  }
}

// ---------------------------------------------------------------------------
extern "C" void kernel_launch(void* const* d_in, const int* in_sizes, int n_in,
                              void* d_out, int out_size, void* d_ws, size_t ws_size,
                              hipStream_t stream) {
  const float* feat   = (const float*)d_in[0];
  const int*   eidx   = (const int*)d_in[1];
  const float* r      = (const float*)d_in[2];
  const float* rel_w  = (const float*)d_in[3];
  const float* rel_b  = (const float*)d_in[4];
  const float* c1_lw  = (const float*)d_in[5];
  const float* c1_lb  = (const float*)d_in[6];
  const float* c1_aiw = (const float*)d_in[7];
  const float* c1_aib = (const float*)d_in[8];
  const float* c1_ajw = (const float*)d_in[9];
  const float* c1_ajb = (const float*)d_in[10];
  const float* c1_eww = (const float*)d_in[11];
  const float* c1_ewb = (const float*)d_in[12];
  const float* c2_lw  = (const float*)d_in[13];
  const float* c2_lb  = (const float*)d_in[14];
  const float* c2_aiw = (const float*)d_in[15];
  const float* c2_aib = (const float*)d_in[16];
  const float* c2_ajw = (const float*)d_in[17];
  const float* c2_ajb = (const float*)d_in[18];
  const float* c2_eww = (const float*)d_in[19];
  const float* c2_ewb = (const float*)d_in[20];
  float* out = (float*)d_out;

  const int N = in_sizes[0] / 64;
  const int E = in_sizes[1] / 2;
  const int* src = eidx;
  const int* dst = eidx + E;

  // ---- workspace carve (~88 MB; ws_size >= 94 MB proven in R6) ----
  // s1, s2, deg are contiguous so one k_zero covers all three.
  float* wsf    = (float*)d_ws;
  float* consts = wsf;                          // 128
  float* ewd1_s = wsf + 128;                    // E (p-order)
  float* ewd2_s = ewd1_s + E;                   // E
  float* ex     = ewd2_s + E;                   // E
  float* s1     = ex + E;                       // N (zero region begin)
  float* s2     = s1 + N;                       // N
  int*   deg    = (int*)(s2 + N);               // N (zero region end)
  float* aid    = (float*)(deg + N);            // N
  float* ajd    = aid + N;                      // N
  float* h1     = ajd + N;                      // N*64 f32 (inter-layer, seq)
  bf16*  x      = (bf16*)(h1 + (size_t)N * 64); // N*64 bf16 (gathered table)
  int*   off    = (int*)(x + (size_t)N * 64);   // N+1
  int*   pos    = off + N + 1;                  // N
  int*   bsum   = pos + N;                      // 256
  int*   bsumx  = bsum + 256;                   // 256
  int*   eid_s  = bsumx + 256;                  // E
  unsigned short* src_s = (unsigned short*)(eid_s + E);  // E u16
  unsigned short* dst_s = src_s + E;                     // E u16
  bf16* r_s = (bf16*)(dst_s + E);                        // E*32 bf16

  const int blocksE   = (E + 255) / 256;
  const int blocksE4  = (E + 1023) / 1024;   // k_deg: 4 edges/thread
  const int blocksP4  = (E + 31) / 32;       // k_perm: 8 groups x 4 edges/block
  const int blocksN   = (N + 255) / 256;
  const int blocksN3  = (3 * N + 255) / 256; // fused zero of s1,s2,deg
  const int gridP     = 2048;

  // ---- shared prep (both layers) ----
  k_zero<<<blocksN3, 256, 0, stream>>>((unsigned int*)s1, 3 * N);
  k_prep<<<1, 64, 0, stream>>>(rel_w, rel_b, c1_eww, c1_ewb, c2_eww, c2_ewb,
                               c1_aib, c1_ajb, c2_aib, c2_ajb, consts);
  k_deg<<<blocksE4, 256, 0, stream>>>(dst, deg, E);
  k_scan_sum<<<blocksN, 256, 0, stream>>>(deg, bsum, N);
  k_scan_bsum<<<1, 256, 0, stream>>>(bsum, bsumx, off, blocksN, N, E);
  k_scan_out<<<blocksN, 256, 0, stream>>>(deg, bsumx, off, pos, N);
  k_fill<<<blocksE, 256, 0, stream>>>(src, dst, pos, eid_s, src_s, dst_s, E);
  k_perm<<<blocksP4, 256, 0, stream>>>(eid_s, r, consts, ewd1_s, ewd2_s, r_s, E);

  // ---- layer 1 ----
  k_x<<<gridP, 256, 0, stream>>>(feat, c1_lw, c1_lb, c1_aiw, c1_ajw, x, aid, ajd, N);
  k_alpha<<<blocksE, 256, 0, stream>>>(src_s, dst_s, aid, ajd, ewd1_s, ex, s1, E);
  k_agg<<<gridP, 256, 0, stream>>>(off, src_s, ex, s1, x, r_s, rel_w, rel_b, h1, N);

  // ---- layer 2 ----
  k_x<<<gridP, 256, 0, stream>>>(h1, c2_lw, c2_lb, c2_aiw, c2_ajw, x, aid, ajd, N);
  k_alpha<<<blocksE, 256, 0, stream>>>(src_s, dst_s, aid, ajd, ewd2_s, ex, s2, E);
  k_agg<<<gridP, 256, 0, stream>>>(off, src_s, ex, s2, x, r_s, rel_w, rel_b, out, N);
}